// Round 16
// baseline (817.716 us; speedup 1.0000x reference)
//
#include <hip/hip_runtime.h>
#include <math.h>

typedef _Float16 f16x8 __attribute__((ext_vector_type(8)));
typedef _Float16 f16x4 __attribute__((ext_vector_type(4)));
typedef float    f32x4 __attribute__((ext_vector_type(4)));
typedef unsigned long long u64;
typedef unsigned int u32;

#define ALOAD(p)    __hip_atomic_load((p), __ATOMIC_RELAXED, __HIP_MEMORY_SCOPE_AGENT)
#define ASTORE(p,v) __hip_atomic_store((p), (v), __ATOMIC_RELAXED, __HIP_MEMORY_SCOPE_AGENT)
#define AADD(p,v)   __hip_atomic_fetch_add((p), (v), __ATOMIC_RELAXED, __HIP_MEMORY_SCOPE_AGENT)

// flg layout (ints, 64B stride): f0[t]=flg[t*16] (role0 phase-t done count),
// f1[t]=flg[1024+t*16], wcnt=flg[2048], convdone=flg[2064]. Monotone, cleared by k_prep.

// ---------------- merged prep: conv(W_ih) | embed | pack1 | pack0 | init ----------------
__global__ __launch_bounds__(256) void k_prep(
    const float* __restrict__ W_ih, _Float16* __restrict__ Wih_h,
    const int* __restrict__ dec, const float* __restrict__ emb,
    float* __restrict__ xf, _Float16* __restrict__ xh,
    const float* __restrict__ W_hh, _Float16* __restrict__ Pk0, _Float16* __restrict__ Pk1,
    const float* __restrict__ h0, const float* __restrict__ c0,
    float* __restrict__ c, _Float16* __restrict__ h0S, _Float16* __restrict__ h1S,
    int* __restrict__ flg) {
  const int bid = blockIdx.x;
  const int tid = threadIdx.x;
  if (bid < 2048) {
    // conv W_ih (f32->f16): 2,097,152 float4 units, four per thread
#pragma unroll
    for (int q = 0; q < 4; ++q) {
      int i = q * 524288 + bid * 256 + tid;
      float4 v = ((const float4*)W_ih)[i];
      f16x4 o;
      o.x = (_Float16)v.x; o.y = (_Float16)v.y; o.z = (_Float16)v.z; o.w = (_Float16)v.w;
      ((f16x4*)Wih_h)[i] = o;
    }
  } else if (bid < 4096) {
    // embedding + relu, 524,288 float4 units; row r = t*32 + b
    int i = (bid - 2048) * 256 + tid;
    int r = i >> 8, c4 = i & 255;
    int b = r & 31, t = r >> 5;
    int tok = dec[b * 64 + t];
    float4 v = ((const float4*)(emb + (size_t)tok * 1024))[c4];
    v.x = fmaxf(v.x, 0.f); v.y = fmaxf(v.y, 0.f); v.z = fmaxf(v.z, 0.f); v.w = fmaxf(v.w, 0.f);
    ((float4*)(xf + (size_t)r * 1024))[c4] = v;
    f16x4 o;
    o.x = (_Float16)v.x; o.y = (_Float16)v.y; o.z = (_Float16)v.z; o.w = (_Float16)v.w;
    ((f16x4*)(xh + (size_t)r * 1024))[c4] = o;
  } else if (bid < 8192) {
    // pack1: [Wih1|Whh1] -> Pk1, 1,048,576 units
    int li = (bid - 4096) * 256 + tid;
    int mat = li >> 19;
    int li2 = li & 524287;
    int row = li2 >> 7, k8l = li2 & 127;
    const float* s = (mat ? (W_hh + (size_t)4096 * 1024) : (W_ih + (size_t)4096 * 1024))
                     + (size_t)row * 1024 + k8l * 8;
    int g = row >> 10, u = row & 1023, jb = u >> 4, col = u & 15;
    int k8g = mat * 128 + k8l;
    int kh = k8g >> 5, rem = k8g & 31, st = rem >> 2, kslot = rem & 3;
    size_t idx = ((size_t)(((jb * 8 + kh) * 8 + st) * 4 + g)) * 64 + kslot * 16 + col;
    f16x8 o;
#pragma unroll
    for (int j = 0; j < 8; ++j) o[j] = (_Float16)s[j];
    *(f16x8*)(Pk1 + idx * 8) = o;
  } else if (bid < 10240) {
    // pack0: Whh0 -> Pk0, 524,288 units
    int li = (bid - 8192) * 256 + tid;
    int row = li >> 7, k8 = li & 127;
    const float* s = W_hh + (size_t)row * 1024 + k8 * 8;
    int g = row >> 10, u = row & 1023, jb = u >> 4, col = u & 15;
    int kh = k8 >> 4, rem = k8 & 15, st = rem >> 2, kslot = rem & 3;
    size_t idx = ((size_t)(((jb * 8 + kh) * 4 + st) * 4 + g)) * 64 + kslot * 16 + col;
    f16x8 o;
#pragma unroll
    for (int j = 0; j < 8; ++j) o[j] = (_Float16)s[j];
    *(f16x8*)(Pk0 + idx * 8) = o;
  } else {
    // init: state slot 0 + flag reset, 65,536 elements
    int i = (bid - 10240) * 256 + tid;
    float hv = h0[i];
    c[i] = c0[i];
    if (i < 32768) h0S[i] = (_Float16)hv;
    else           h1S[i - 32768] = (_Float16)hv;
    if (i < 2080) flg[i] = 0;
  }
}

// ---------------- gx GEMM, 256x256 tiles ----------------
__global__ __launch_bounds__(512) void k_gemm0b(const _Float16* __restrict__ A,
                                                const _Float16* __restrict__ Bm,
                                                const float* __restrict__ bias0,
                                                const float* __restrict__ bias1,
                                                float* __restrict__ C) {
  __shared__ _Float16 lds2[32768];
  const int tid = threadIdx.x;
  const int lane = tid & 63;
  const int w = tid >> 6;
  const int wm = w >> 2, wn = w & 3;
  const int r0 = tid & 255, kb0 = tid >> 8;
  const int m = blockIdx.y, nt = blockIdx.x;
  const _Float16* Ab = A + (size_t)m * 256 * 1024;
  const _Float16* Bb = Bm + (size_t)nt * 256 * 1024;
  f16x8 pa0, pa1, pb0, pb1;
  pa0 = *(const f16x8*)(Ab + r0 * 1024 + kb0 * 8);
  pa1 = *(const f16x8*)(Ab + r0 * 1024 + (kb0 + 2) * 8);
  pb0 = *(const f16x8*)(Bb + r0 * 1024 + kb0 * 8);
  pb1 = *(const f16x8*)(Bb + r0 * 1024 + (kb0 + 2) * 8);
  f32x4 acc[8][4] = {};
  for (int kc = 0; kc < 32; ++kc) {
    _Float16* Ac = lds2 + (kc & 1) * 8192;
    _Float16* Bc = lds2 + 16384 + (kc & 1) * 8192;
    *(f16x8*)(Ac + kb0 * 2048 + r0 * 8) = pa0;
    *(f16x8*)(Ac + (kb0 + 2) * 2048 + r0 * 8) = pa1;
    *(f16x8*)(Bc + kb0 * 2048 + r0 * 8) = pb0;
    *(f16x8*)(Bc + (kb0 + 2) * 2048 + r0 * 8) = pb1;
    if (kc + 1 < 32) {
      int ko = (kc + 1) * 32;
      pa0 = *(const f16x8*)(Ab + r0 * 1024 + ko + kb0 * 8);
      pa1 = *(const f16x8*)(Ab + r0 * 1024 + ko + (kb0 + 2) * 8);
      pb0 = *(const f16x8*)(Bb + r0 * 1024 + ko + kb0 * 8);
      pb1 = *(const f16x8*)(Bb + r0 * 1024 + ko + (kb0 + 2) * 8);
    }
    __syncthreads();
    const int kb = lane >> 4;
    f16x8 af[8], bf[4];
#pragma unroll
    for (int mf = 0; mf < 8; ++mf) {
      int row = wm * 128 + mf * 16 + (lane & 15);
      af[mf] = *(const f16x8*)(Ac + kb * 2048 + row * 8);
    }
#pragma unroll
    for (int nf = 0; nf < 4; ++nf) {
      int row = wn * 64 + nf * 16 + (lane & 15);
      bf[nf] = *(const f16x8*)(Bc + kb * 2048 + row * 8);
    }
#pragma unroll
    for (int mf = 0; mf < 8; ++mf)
#pragma unroll
      for (int nf = 0; nf < 4; ++nf)
        acc[mf][nf] = __builtin_amdgcn_mfma_f32_16x16x32_f16(af[mf], bf[nf], acc[mf][nf], 0, 0, 0);
  }
  const int rl = (lane >> 4) * 4;
#pragma unroll
  for (int mf = 0; mf < 8; ++mf) {
#pragma unroll
    for (int nf = 0; nf < 4; ++nf) {
#pragma unroll
      for (int j = 0; j < 4; ++j) {
        int rg = m * 256 + wm * 128 + mf * 16 + rl + j;
        int ng = nt * 256 + wn * 64 + nf * 16 + (lane & 15);
        C[(size_t)rg * 8192 + ng] = acc[mf][nf][j] + bias0[ng] + bias1[ng];
      }
    }
  }
}

// ---------------- persistent LSTM phases, decoupled role chains ----------------
// Dependencies (t = timestep 0..63):
//   role0(t): needs h0S[t]   <- role0(t-1)  [f0[t-1]>=64]; ipf slot reuse bound: f1[t-4]>=64.
//   role1(t): needs h0S[t+1], ipfS[t&3] <- role0(t) [f0[t]>=64]; h1S[t] <- role1(t-1) [f1[t-1]>=64].
// All cross-block data write-once per launch (h0S/h1S/outs rotating slots; ipfS 4-deep,
// WAR bounded by the f1[t-4] gate). sc1 writes -> syncthreads drain -> counter bump ->
// gated plain cached reads (the R11-proven visibility contract).
template <int ROLE>
__device__ __forceinline__ void run_phases(
    int jb, const _Float16* __restrict__ Pk,
    const float* __restrict__ gx, const float* __restrict__ x_f,
    float* __restrict__ c_f,
    _Float16* __restrict__ h0S, _Float16* __restrict__ h1S,
    float* __restrict__ ipfS,
    float* __restrict__ outs_f, _Float16* __restrict__ outs_h,
    float* __restrict__ outHT, float* __restrict__ outCT,
    int* flg, _Float16* As) {
  constexpr int S = ROLE ? 8 : 4;
  constexpr int NHALF = ROLE ? 2 : 1;
  constexpr int RSH = ROLE ? 8 : 7;
  constexpr int K8M = ROLE ? 255 : 127;
  const int u0 = jb * 16;
  const int tid = threadIdx.x;
  const int lane = tid & 63;
  const int kh = tid >> 6;
  const int col = lane & 15;
  const int kslot = lane >> 4;

  float* cst = c_f + ROLE * 32768;
  const float* gxbase = gx + (ROLE ? 4096 : 0);
  const int cb = tid >> 4, cul = tid & 15, cu = u0 + cul;

  const _Float16* pkbase = Pk + ((size_t)(jb * 8 + kh) * S) * 4 * 512 + lane * 8;
  const int a0off = col * 2056 + kh * S * 32 + kslot * 8;
  const int a1off = a0off + 16 * 2056;

  // weights pinned in registers for the whole recurrence
  f16x8 wreg[S * 4];
#pragma unroll
  for (int i = 0; i < S * 4; ++i) wreg[i] = *(const f16x8*)(pkbase + i * 512);

  for (int t = 0; t < 64; ++t) {
    // ---- dependency gates (monotone counters; spin on tid 0 only) ----
    if (tid == 0) {
      if (ROLE == 0) {
        if (t > 0)  while (ALOAD(flg + (t - 1) * 16) < 64) __builtin_amdgcn_s_sleep(1);
        if (t >= 4) while (ALOAD(flg + 1024 + (t - 4) * 16) < 64) __builtin_amdgcn_s_sleep(1);
      } else {
        while (ALOAD(flg + t * 16) < 64) __builtin_amdgcn_s_sleep(1);
        if (t > 0) while (ALOAD(flg + 1024 + (t - 1) * 16) < 64) __builtin_amdgcn_s_sleep(1);
      }
    }
    __syncthreads();

    const _Float16* h0r = h0S + (size_t)(ROLE == 0 ? t : t + 1) * 32768;
    _Float16* h0w = h0S + (size_t)(t + 1) * 32768;          // role0 only
    const _Float16* h1r = h1S + (size_t)t * 32768;          // role1 only
    _Float16* h1w = h1S + (size_t)(t + 1) * 32768;          // role1 only
    const float* ipfr = ipfS + (size_t)(t & 3) * 32768;     // role1 read
    float* ipfw = ipfS + (size_t)(t & 3) * 32768;           // role0 write

    const float* gxr = gxbase + (size_t)(t * 32 + cb) * 8192;
    float pg0 = gxr[cu], pg1 = gxr[1024 + cu], pg2 = gxr[2048 + cu], pg3 = gxr[3072 + cu];
    float pc = cst[cb * 1024 + cu];
    float px = 0.f, pip = 0.f;
    if (ROLE == 0) px = x_f[(size_t)(t * 32 + cb) * 1024 + cu];
    else           pip = ALOAD(ipfr + cb * 1024 + cu);

    // ---- state -> LDS (plain cached loads; write-once-fresh addresses) ----
#pragma unroll
    for (int hf = 0; hf < NHALF; ++hf) {
      f16x8 sreg[8];
#pragma unroll
      for (int i = 0; i < 8; ++i) {
        int fr = (hf * 8 + i) * 512 + tid;
        int row = fr >> RSH, k8 = fr & K8M;
        const _Float16* s;
        if (ROLE == 0) s = h0r + row * 1024 + k8 * 8;
        else           s = (k8 < 128) ? (h0r + row * 1024 + k8 * 8)
                                      : (h1r + row * 1024 + (k8 - 128) * 8);
        sreg[i] = *(const f16x8*)s;
      }
#pragma unroll
      for (int i = 0; i < 8; ++i) {
        int fr = (hf * 8 + i) * 512 + tid;
        int row = fr >> RSH, k8 = fr & K8M;
        *(f16x8*)(As + row * 2056 + k8 * 8) = sreg[i];
      }
    }
    __syncthreads();

    f32x4 acc[2][4] = {};
#pragma unroll
    for (int s2 = 0; s2 < S; ++s2) {
      f16x8 a0 = *(const f16x8*)(As + a0off + s2 * 32);
      f16x8 a1 = *(const f16x8*)(As + a1off + s2 * 32);
      acc[0][0] = __builtin_amdgcn_mfma_f32_16x16x32_f16(a0, wreg[s2 * 4 + 0], acc[0][0], 0, 0, 0);
      acc[1][0] = __builtin_amdgcn_mfma_f32_16x16x32_f16(a1, wreg[s2 * 4 + 0], acc[1][0], 0, 0, 0);
      acc[0][1] = __builtin_amdgcn_mfma_f32_16x16x32_f16(a0, wreg[s2 * 4 + 1], acc[0][1], 0, 0, 0);
      acc[1][1] = __builtin_amdgcn_mfma_f32_16x16x32_f16(a1, wreg[s2 * 4 + 1], acc[1][1], 0, 0, 0);
      acc[0][2] = __builtin_amdgcn_mfma_f32_16x16x32_f16(a0, wreg[s2 * 4 + 2], acc[0][2], 0, 0, 0);
      acc[1][2] = __builtin_amdgcn_mfma_f32_16x16x32_f16(a1, wreg[s2 * 4 + 2], acc[1][2], 0, 0, 0);
      acc[0][3] = __builtin_amdgcn_mfma_f32_16x16x32_f16(a0, wreg[s2 * 4 + 3], acc[0][3], 0, 0, 0);
      acc[1][3] = __builtin_amdgcn_mfma_f32_16x16x32_f16(a1, wreg[s2 * 4 + 3], acc[1][3], 0, 0, 0);
    }
    __syncthreads();

    float (*gs)[32][68] = (float (*)[32][68])(void*)As;
    const int rl = kslot * 4;
    if (kh < 4) {
#pragma unroll
      for (int m = 0; m < 2; ++m)
#pragma unroll
        for (int g = 0; g < 4; ++g)
#pragma unroll
          for (int j = 0; j < 4; ++j)
            gs[kh][m * 16 + rl + j][g * 16 + col] = acc[m][g][j];
    }
    __syncthreads();
    if (kh >= 4) {
#pragma unroll
      for (int m = 0; m < 2; ++m)
#pragma unroll
        for (int g = 0; g < 4; ++g)
#pragma unroll
          for (int j = 0; j < 4; ++j)
            gs[kh - 4][m * 16 + rl + j][g * 16 + col] += acc[m][g][j];
    }
    __syncthreads();

    {
      float ig = pg0, fg = pg1, gg = pg2, og = pg3;
#pragma unroll
      for (int cc = 0; cc < 4; ++cc) {
        ig += gs[cc][cb][cul];
        fg += gs[cc][cb][16 + cul];
        gg += gs[cc][cb][32 + cul];
        og += gs[cc][cb][48 + cul];
      }
      float si = 1.f / (1.f + expf(-ig));
      float sf = 1.f / (1.f + expf(-fg));
      float so = 1.f / (1.f + expf(-og));
      float ci = sf * pc + si * tanhf(gg);
      float hi = so * tanhf(ci);
      cst[cb * 1024 + cu] = ci;
      if (t == 63) {
        outHT[ROLE * 32768 + cb * 1024 + cu] = hi;
        outCT[ROLE * 32768 + cb * 1024 + cu] = ci;
      }
      if (ROLE == 0) {
        float hn = __shfl_down(hi, 1);
        float ipv = hi + px;
        float ipn = __shfl_down(ipv, 1);
        if ((cul & 1) == 0) {
          union { _Float16 h[2]; u32 v; } ph;
          ph.h[0] = (_Float16)hi; ph.h[1] = (_Float16)hn;
          ASTORE((u32*)(h0w + cb * 1024 + cu), ph.v);
          union { float f[2]; u64 v; } pi;
          pi.f[0] = ipv; pi.f[1] = ipn;
          ASTORE((u64*)(ipfw + cb * 1024 + cu), pi.v);
        }
      } else {
        float hn = __shfl_down(hi, 1);
        float ro = hi + pip;
        float rn = __shfl_down(ro, 1);
        if ((cul & 1) == 0) {
          union { _Float16 h[2]; u32 v; } ph;
          ph.h[0] = (_Float16)hi; ph.h[1] = (_Float16)hn;
          ASTORE((u32*)(h1w + cb * 1024 + cu), ph.v);
          union { _Float16 h[2]; u32 v; } po;
          po.h[0] = (_Float16)ro; po.h[1] = (_Float16)rn;
          ASTORE((u32*)(outs_h + (size_t)(t * 32 + cb) * 1024 + cu), po.v);
        }
        outs_f[(size_t)(t * 32 + cb) * 1024 + cu] = ro;
      }
    }
    // ---- drain stores, then signal phase completion ----
    __syncthreads();
    if (tid == 0) AADD(flg + (ROLE ? 1024 : 0) + t * 16, 1);
  }
}

// ---------------- clsW f32->f16 conversion by consumer blocks ----------------
__device__ __forceinline__ void conv_clsW(const float* __restrict__ src,
                                          _Float16* __restrict__ dst, int cb) {
  for (int i = cb * 512 + threadIdx.x; i < 4096000; i += 65536) {
    const f32x4* s = (const f32x4*)(src + (size_t)i * 8);
    f32x4 v0 = __builtin_nontemporal_load(s);
    f32x4 v1 = __builtin_nontemporal_load(s + 1);
    union { _Float16 h[8]; u64 q[2]; } o;
    o.h[0] = (_Float16)v0.x; o.h[1] = (_Float16)v0.y;
    o.h[2] = (_Float16)v0.z; o.h[3] = (_Float16)v0.w;
    o.h[4] = (_Float16)v1.x; o.h[5] = (_Float16)v1.y;
    o.h[6] = (_Float16)v1.z; o.h[7] = (_Float16)v1.w;
    u64* d = (u64*)(dst + (size_t)i * 8);
    ASTORE(d, o.q[0]);
    ASTORE(d + 1, o.q[1]);
  }
}

// ---------------- logits GEMM consumer: 256x256 tiles, dynamic work-steal ----------------
// m-tile m needs outs for t <= 8m+7  ->  wait f1[min(8m+7,63)] >= 64.
__device__ __forceinline__ void run_consumer(
    const _Float16* __restrict__ outs_h, const _Float16* __restrict__ clsW_h,
    const float* __restrict__ cls_b, float* __restrict__ out, int* flg, _Float16* lds) {
  __shared__ int tau_s;
  const int tid = threadIdx.x;
  const int lane = tid & 63;
  const int w = tid >> 6;
  const int wm = w >> 2, wn = w & 3;
  int* wcnt = flg + 2048;
  const int r0 = tid & 255, kb0 = tid >> 8;

  if (tid == 0) {
    while (ALOAD(flg + 2064) < 128) __builtin_amdgcn_s_sleep(16);
  }
  __syncthreads();

  for (;;) {
    if (tid == 0) tau_s = AADD(wcnt, 1);
    __syncthreads();
    int tau = tau_s;
    if (tau >= 1000) break;
    int m = tau / 125, nt = tau - m * 125;
    if (tid == 0) {
      int mm = 8 * m + 7; if (mm > 63) mm = 63;
      while (ALOAD(flg + 1024 + mm * 16) < 64) __builtin_amdgcn_s_sleep(64);
    }
    __syncthreads();

    const _Float16* Ab = outs_h + (size_t)m * 256 * 1024;
    const _Float16* Bb = clsW_h + (size_t)nt * 256 * 1024;
    f16x8 pa0, pa1, pb0, pb1;
    pa0 = *(const f16x8*)(Ab + r0 * 1024 + kb0 * 8);
    pa1 = *(const f16x8*)(Ab + r0 * 1024 + (kb0 + 2) * 8);
    pb0 = *(const f16x8*)(Bb + r0 * 1024 + kb0 * 8);
    pb1 = *(const f16x8*)(Bb + r0 * 1024 + (kb0 + 2) * 8);
    f32x4 acc[8][4] = {};
    for (int kc = 0; kc < 32; ++kc) {
      _Float16* Ac = lds + (kc & 1) * 8192;
      _Float16* Bc = lds + 16384 + (kc & 1) * 8192;
      *(f16x8*)(Ac + kb0 * 2048 + r0 * 8) = pa0;
      *(f16x8*)(Ac + (kb0 + 2) * 2048 + r0 * 8) = pa1;
      *(f16x8*)(Bc + kb0 * 2048 + r0 * 8) = pb0;
      *(f16x8*)(Bc + (kb0 + 2) * 2048 + r0 * 8) = pb1;
      if (kc + 1 < 32) {
        int ko = (kc + 1) * 32;
        pa0 = *(const f16x8*)(Ab + r0 * 1024 + ko + kb0 * 8);
        pa1 = *(const f16x8*)(Ab + r0 * 1024 + ko + (kb0 + 2) * 8);
        pb0 = *(const f16x8*)(Bb + r0 * 1024 + ko + kb0 * 8);
        pb1 = *(const f16x8*)(Bb + r0 * 1024 + ko + (kb0 + 2) * 8);
      }
      __syncthreads();
      const int kb = lane >> 4;
      f16x8 af[8], bf[4];
#pragma unroll
      for (int mf = 0; mf < 8; ++mf) {
        int row = wm * 128 + mf * 16 + (lane & 15);
        af[mf] = *(const f16x8*)(Ac + kb * 2048 + row * 8);
      }
#pragma unroll
      for (int nf = 0; nf < 4; ++nf) {
        int row = wn * 64 + nf * 16 + (lane & 15);
        bf[nf] = *(const f16x8*)(Bc + kb * 2048 + row * 8);
      }
#pragma unroll
      for (int mf = 0; mf < 8; ++mf)
#pragma unroll
        for (int nf = 0; nf < 4; ++nf)
          acc[mf][nf] = __builtin_amdgcn_mfma_f32_16x16x32_f16(af[mf], bf[nf], acc[mf][nf], 0, 0, 0);
    }
    const int rl = (lane >> 4) * 4;
#pragma unroll
    for (int mf = 0; mf < 8; ++mf) {
#pragma unroll
      for (int nf = 0; nf < 4; ++nf) {
#pragma unroll
        for (int j = 0; j < 4; ++j) {
          int rg = m * 256 + wm * 128 + mf * 16 + rl + j;
          int tt = rg >> 5, b = rg & 31;
          int ng = nt * 256 + wn * 64 + nf * 16 + (lane & 15);
          __builtin_nontemporal_store(acc[mf][nf][j] + cls_b[ng],
                                      &out[(size_t)(b * 64 + tt) * 32000 + ng]);
        }
      }
    }
  }
}

__global__ __launch_bounds__(512, 1) void k_lstm_fused(
    const _Float16* __restrict__ Pk0, const _Float16* __restrict__ Pk1,
    const float* __restrict__ gx, const float* __restrict__ x_f,
    float* __restrict__ c_f,
    _Float16* __restrict__ h0S, _Float16* __restrict__ h1S,
    float* __restrict__ ipfS,
    float* __restrict__ outs_f, _Float16* __restrict__ outs_h,
    const float* __restrict__ cls_W, _Float16* __restrict__ clsW_h,
    const float* __restrict__ cls_b,
    float* __restrict__ out_logits,
    float* __restrict__ outHT, float* __restrict__ outCT,
    int* flg) {
  __shared__ _Float16 As[32 * 2056];  // 131,584 B (1 block/CU -> 256 blocks co-resident)
  const int bid = blockIdx.x;
  if (bid < 64) {
    run_phases<0>(bid & 63, Pk0, gx, x_f, c_f, h0S, h1S, ipfS,
                  outs_f, outs_h, outHT, outCT, flg, As);
  } else if (bid < 128) {
    run_phases<1>(bid & 63, Pk1, gx, x_f, c_f, h0S, h1S, ipfS,
                  outs_f, outs_h, outHT, outCT, flg, As);
  } else {
    conv_clsW(cls_W, clsW_h, bid - 128);
    __syncthreads();
    if (threadIdx.x == 0) AADD(flg + 2064, 1);
  }
  run_consumer(outs_h, clsW_h, cls_b, out_logits, flg, As);
}

// ---------------- batched dot-attention + softmax ----------------
__global__ __launch_bounds__(256) void k_attn(const float* __restrict__ outs,
                                              const float* __restrict__ enc,
                                              float* __restrict__ att) {
  __shared__ float o_s[8][1024];
  __shared__ float sc[8][128];
  const int tid = threadIdx.x;
  const int lane = tid & 63;
  const int w = tid >> 6;
  const int b = blockIdx.x >> 3;
  const int t0 = (blockIdx.x & 7) * 8;
#pragma unroll
  for (int ii = 0; ii < 8; ++ii) {
    int idx = tid + ii * 256;
    int tt = idx >> 8, c4 = idx & 255;
    ((float4*)&o_s[tt][0])[c4] =
        *(const float4*)(outs + (size_t)((t0 + tt) * 32 + b) * 1024 + (size_t)c4 * 4);
  }
  __syncthreads();
  for (int si = 0; si < 32; ++si) {
    int s = w * 32 + si;
    float av[8] = {0, 0, 0, 0, 0, 0, 0, 0};
    const float* er = enc + (size_t)(b * 128 + s) * 1024;
#pragma unroll
    for (int i = 0; i < 4; ++i) {
      int k = i * 256 + lane * 4;
      float4 e = *(const float4*)(er + k);
#pragma unroll
      for (int tt = 0; tt < 8; ++tt) {
        float4 o = *(const float4*)&o_s[tt][k];
        av[tt] += e.x * o.x + e.y * o.y + e.z * o.z + e.w * o.w;
      }
    }
#pragma unroll
    for (int tt = 0; tt < 8; ++tt) {
      float v = av[tt];
#pragma unroll
      for (int off = 32; off > 0; off >>= 1) v += __shfl_down(v, off);
      if (lane == 0) sc[tt][s] = v;
    }
  }
  __syncthreads();
#pragma unroll
  for (int pp = 0; pp < 2; ++pp) {
    int tt = w + pp * 4;
    float a = sc[tt][lane], b2 = sc[tt][64 + lane];
    float m = fmaxf(a, b2);
#pragma unroll
    for (int off = 32; off > 0; off >>= 1) m = fmaxf(m, __shfl_xor(m, off));
    float e0 = expf(a - m), e1 = expf(b2 - m);
    float ss = e0 + e1;
#pragma unroll
    for (int off = 32; off > 0; off >>= 1) ss += __shfl_xor(ss, off);
    float r = 1.f / ss;
    att[(size_t)b * 8192 + (size_t)lane * 64 + t0 + tt] = e0 * r;
    att[(size_t)b * 8192 + (size_t)(64 + lane) * 64 + t0 + tt] = e1 * r;
  }
}

extern "C" void kernel_launch(void* const* d_in, const int* in_sizes, int n_in,
                              void* d_out, int out_size, void* d_ws, size_t ws_size,
                              hipStream_t stream) {
  const int*   dec   = (const int*)d_in[0];
  const float* h0    = (const float*)d_in[1];
  const float* c0    = (const float*)d_in[2];
  const float* enc   = (const float*)d_in[3];
  const float* emb   = (const float*)d_in[4];
  const float* W_ih  = (const float*)d_in[5];
  const float* W_hh  = (const float*)d_in[6];
  const float* b_ih  = (const float*)d_in[7];
  const float* b_hh  = (const float*)d_in[8];
  const float* cls_W = (const float*)d_in[9];
  const float* cls_b = (const float*)d_in[10];
  float* out = (float*)d_out;
  char* ws = (char*)d_ws;

  float*    x_f    = (float*)(ws + 0);                // [2048][1024] f32, ends 8388608
  _Float16* Pk0    = (_Float16*)(ws + 8388608);       // 8MB packed Whh0, ends 16777216
  _Float16* h0S    = (_Float16*)(ws + 16777216);      // 65 slots, ends 21037056
  _Float16* h1S    = (_Float16*)(ws + 21037056);      // 65 slots, ends 25296896
  float*    ipfS   = (float*)(ws + 25296896);         // 4 slots x 128KB, ends 25821184
  int*      flg    = (int*)(ws + 25821184);           // 2080 ints, ends ~25829504
  _Float16* Pk1    = (_Float16*)(ws + 29360128);      // 16MB, ends 46137344
  _Float16* clsW_h = (_Float16*)(ws + 46137344);      // 65.5MB, ends 111673344 (filled in-kernel)
  _Float16* Wih_h  = (_Float16*)(ws + 54657024);      // 16.7MB inside clsW_h, ends 71434240
  _Float16* x_h    = (_Float16*)(ws + 71434240);      // 4MB inside clsW_h, ends 75628544
                                                      // (Wih_h/x_h dead after k_gemm0b; conv_clsW
                                                      //  overwrites them; consumers read clsW_h
                                                      //  only after flg[2064]==128)
  float*    gx     = (float*)(ws + 111673344);        // [2048][8192] f32, ends 178782208
  float*    outs_f = (float*)(ws + 178782208);        // 8MB, ends 187170816
  _Float16* outs_h = (_Float16*)(ws + 187170816);     // 4MB, ends 191365120
  float*    c_f    = (float*)(ws + 191627264);        // [2][32][1024] f32

  k_prep<<<10496, 256, 0, stream>>>(W_ih, Wih_h, dec, emb, x_f, x_h,
                                    W_hh, Pk0, Pk1, h0, c0, c_f, h0S, h1S, flg);
  k_gemm0b<<<dim3(32, 8), 512, 0, stream>>>(x_h, Wih_h, b_ih, b_hh, gx);

  k_lstm_fused<<<256, 512, 0, stream>>>(Pk0, Pk1, gx, x_f, c_f,
                                        h0S, h1S, ipfS,
                                        outs_f, outs_h, cls_W, clsW_h, cls_b, out,
                                        out + (size_t)65536000, out + (size_t)65601536,
                                        flg);

  k_attn<<<256, 256, 0, stream>>>(outs_f, enc, out + (size_t)65667072);
}

// Round 17
// 665.156 us; speedup vs baseline: 1.2294x; 1.2294x over previous
//
#include <hip/hip_runtime.h>
#include <math.h>

typedef _Float16 f16x8 __attribute__((ext_vector_type(8)));
typedef _Float16 f16x4 __attribute__((ext_vector_type(4)));
typedef float    f32x4 __attribute__((ext_vector_type(4)));
typedef unsigned long long u64;
typedef unsigned int u32;

#define ALOAD(p)    __hip_atomic_load((p), __ATOMIC_RELAXED, __HIP_MEMORY_SCOPE_AGENT)
#define ASTORE(p,v) __hip_atomic_store((p), (v), __ATOMIC_RELAXED, __HIP_MEMORY_SCOPE_AGENT)

// ---------------- merged prep: conv(W_ih) | embed | pack1 | pack0 | init ----------------
__global__ __launch_bounds__(256) void k_prep(
    const float* __restrict__ W_ih, _Float16* __restrict__ Wih_h,
    const int* __restrict__ dec, const float* __restrict__ emb,
    float* __restrict__ xf, _Float16* __restrict__ xh,
    const float* __restrict__ W_hh, _Float16* __restrict__ Pk0, _Float16* __restrict__ Pk1,
    const float* __restrict__ h0, const float* __restrict__ c0,
    float* __restrict__ c, _Float16* __restrict__ h0S, _Float16* __restrict__ h1S,
    int* __restrict__ bar) {
  const int bid = blockIdx.x;
  const int tid = threadIdx.x;
  if (bid < 2048) {
    // conv W_ih (f32->f16): 2,097,152 float4 units, four per thread
#pragma unroll
    for (int q = 0; q < 4; ++q) {
      int i = q * 524288 + bid * 256 + tid;
      float4 v = ((const float4*)W_ih)[i];
      f16x4 o;
      o.x = (_Float16)v.x; o.y = (_Float16)v.y; o.z = (_Float16)v.z; o.w = (_Float16)v.w;
      ((f16x4*)Wih_h)[i] = o;
    }
  } else if (bid < 4096) {
    // embedding + relu, 524,288 float4 units; row r = t*32 + b
    int i = (bid - 2048) * 256 + tid;
    int r = i >> 8, c4 = i & 255;
    int b = r & 31, t = r >> 5;
    int tok = dec[b * 64 + t];
    float4 v = ((const float4*)(emb + (size_t)tok * 1024))[c4];
    v.x = fmaxf(v.x, 0.f); v.y = fmaxf(v.y, 0.f); v.z = fmaxf(v.z, 0.f); v.w = fmaxf(v.w, 0.f);
    ((float4*)(xf + (size_t)r * 1024))[c4] = v;
    f16x4 o;
    o.x = (_Float16)v.x; o.y = (_Float16)v.y; o.z = (_Float16)v.z; o.w = (_Float16)v.w;
    ((f16x4*)(xh + (size_t)r * 1024))[c4] = o;
  } else if (bid < 8192) {
    // pack1: [Wih1|Whh1] -> Pk1, 1,048,576 units
    int li = (bid - 4096) * 256 + tid;
    int mat = li >> 19;
    int li2 = li & 524287;
    int row = li2 >> 7, k8l = li2 & 127;
    const float* s = (mat ? (W_hh + (size_t)4096 * 1024) : (W_ih + (size_t)4096 * 1024))
                     + (size_t)row * 1024 + k8l * 8;
    int g = row >> 10, u = row & 1023, jb = u >> 4, col = u & 15;
    int k8g = mat * 128 + k8l;
    int kh = k8g >> 5, rem = k8g & 31, st = rem >> 2, kslot = rem & 3;
    size_t idx = ((size_t)(((jb * 8 + kh) * 8 + st) * 4 + g)) * 64 + kslot * 16 + col;
    f16x8 o;
#pragma unroll
    for (int j = 0; j < 8; ++j) o[j] = (_Float16)s[j];
    *(f16x8*)(Pk1 + idx * 8) = o;
  } else if (bid < 10240) {
    // pack0: Whh0 -> Pk0, 524,288 units
    int li = (bid - 8192) * 256 + tid;
    int row = li >> 7, k8 = li & 127;
    const float* s = W_hh + (size_t)row * 1024 + k8 * 8;
    int g = row >> 10, u = row & 1023, jb = u >> 4, col = u & 15;
    int kh = k8 >> 4, rem = k8 & 15, st = rem >> 2, kslot = rem & 3;
    size_t idx = ((size_t)(((jb * 8 + kh) * 4 + st) * 4 + g)) * 64 + kslot * 16 + col;
    f16x8 o;
#pragma unroll
    for (int j = 0; j < 8; ++j) o[j] = (_Float16)s[j];
    *(f16x8*)(Pk0 + idx * 8) = o;
  } else {
    // init: state slot 0 + barrier reset, 65,536 elements
    int i = (bid - 10240) * 256 + tid;
    float hv = h0[i];
    c[i] = c0[i];
    if (i < 32768) h0S[i] = (_Float16)hv;
    else           h1S[i - 32768] = (_Float16)hv;
    if (i < 640) bar[i] = 0;
  }
}

// ---------------- gx GEMM, 256x256 tiles (proven consumer-tile body) ----------------
// gx[2048][8192] = x_h @ Wih_h^T + b_ih + b_hh; grid (32 n-tiles, 8 m-tiles), 512 thr.
__global__ __launch_bounds__(512) void k_gemm0b(const _Float16* __restrict__ A,
                                                const _Float16* __restrict__ Bm,
                                                const float* __restrict__ bias0,
                                                const float* __restrict__ bias1,
                                                float* __restrict__ C) {
  __shared__ _Float16 lds2[32768];  // A dbuf 2x8192 + B dbuf 2x8192 (64 KB)
  const int tid = threadIdx.x;
  const int lane = tid & 63;
  const int w = tid >> 6;
  const int wm = w >> 2, wn = w & 3;      // 2x4 waves; wave tile 128x64
  const int r0 = tid & 255, kb0 = tid >> 8;
  const int m = blockIdx.y, nt = blockIdx.x;
  const _Float16* Ab = A + (size_t)m * 256 * 1024;
  const _Float16* Bb = Bm + (size_t)nt * 256 * 1024;
  f16x8 pa0, pa1, pb0, pb1;
  pa0 = *(const f16x8*)(Ab + r0 * 1024 + kb0 * 8);
  pa1 = *(const f16x8*)(Ab + r0 * 1024 + (kb0 + 2) * 8);
  pb0 = *(const f16x8*)(Bb + r0 * 1024 + kb0 * 8);
  pb1 = *(const f16x8*)(Bb + r0 * 1024 + (kb0 + 2) * 8);
  f32x4 acc[8][4] = {};
  for (int kc = 0; kc < 32; ++kc) {
    _Float16* Ac = lds2 + (kc & 1) * 8192;
    _Float16* Bc = lds2 + 16384 + (kc & 1) * 8192;
    *(f16x8*)(Ac + kb0 * 2048 + r0 * 8) = pa0;
    *(f16x8*)(Ac + (kb0 + 2) * 2048 + r0 * 8) = pa1;
    *(f16x8*)(Bc + kb0 * 2048 + r0 * 8) = pb0;
    *(f16x8*)(Bc + (kb0 + 2) * 2048 + r0 * 8) = pb1;
    if (kc + 1 < 32) {
      int ko = (kc + 1) * 32;
      pa0 = *(const f16x8*)(Ab + r0 * 1024 + ko + kb0 * 8);
      pa1 = *(const f16x8*)(Ab + r0 * 1024 + ko + (kb0 + 2) * 8);
      pb0 = *(const f16x8*)(Bb + r0 * 1024 + ko + kb0 * 8);
      pb1 = *(const f16x8*)(Bb + r0 * 1024 + ko + (kb0 + 2) * 8);
    }
    __syncthreads();
    const int kb = lane >> 4;
    f16x8 af[8], bf[4];
#pragma unroll
    for (int mf = 0; mf < 8; ++mf) {
      int row = wm * 128 + mf * 16 + (lane & 15);
      af[mf] = *(const f16x8*)(Ac + kb * 2048 + row * 8);
    }
#pragma unroll
    for (int nf = 0; nf < 4; ++nf) {
      int row = wn * 64 + nf * 16 + (lane & 15);
      bf[nf] = *(const f16x8*)(Bc + kb * 2048 + row * 8);
    }
#pragma unroll
    for (int mf = 0; mf < 8; ++mf)
#pragma unroll
      for (int nf = 0; nf < 4; ++nf)
        acc[mf][nf] = __builtin_amdgcn_mfma_f32_16x16x32_f16(af[mf], bf[nf], acc[mf][nf], 0, 0, 0);
  }
  const int rl = (lane >> 4) * 4;
#pragma unroll
  for (int mf = 0; mf < 8; ++mf) {
#pragma unroll
    for (int nf = 0; nf < 4; ++nf) {
#pragma unroll
      for (int j = 0; j < 4; ++j) {
        int rg = m * 256 + wm * 128 + mf * 16 + rl + j;
        int ng = nt * 256 + wn * 64 + nf * 16 + (lane & 15);
        C[(size_t)rg * 8192 + ng] = acc[mf][nf][j] + bias0[ng] + bias1[ng];
      }
    }
  }
}

// ---------------- two-level tree barrier (RELAXED-only) ----------------
__device__ __forceinline__ void gbar(int* bar) {
  __syncthreads();
  if (threadIdx.x == 0) {
    int* gen = bar + 544;
    int g = ALOAD(gen);
    int grp = blockIdx.x >> 3;
    int a = __hip_atomic_fetch_add(bar + grp * 32, 1, __ATOMIC_RELAXED, __HIP_MEMORY_SCOPE_AGENT);
    if (a == 7) {
      ASTORE(bar + grp * 32, 0);
      int r = __hip_atomic_fetch_add(bar + 512, 1, __ATOMIC_RELAXED, __HIP_MEMORY_SCOPE_AGENT);
      if (r == 15) {
        ASTORE(bar + 512, 0);
        ASTORE(gen, g + 1);
      }
    }
    while (ALOAD(gen) == g) __builtin_amdgcn_s_sleep(1);
  }
  __syncthreads();
}

// ---------------- persistent LSTM phases (blocks 0..127) ----------------
// Write-once rotating state slots: sc1 writes, plain cached reads (addresses never
// read before their unique write; deterministic across replays).
template <int ROLE>
__device__ __forceinline__ void run_phases(
    int jb, const _Float16* __restrict__ Pk,
    const float* __restrict__ gx, const float* __restrict__ x_f,
    float* __restrict__ c_f,
    _Float16* __restrict__ h0S, _Float16* __restrict__ h1S,
    float* __restrict__ ipfA, float* __restrict__ ipfB,
    float* __restrict__ outs_f, _Float16* __restrict__ outs_h,
    float* __restrict__ outHT, float* __restrict__ outCT,
    int* bar, _Float16* As) {
  constexpr int S = ROLE ? 8 : 4;
  constexpr int NHALF = ROLE ? 2 : 1;
  constexpr int RSH = ROLE ? 8 : 7;
  constexpr int K8M = ROLE ? 255 : 127;
  const int u0 = jb * 16;
  const int tid = threadIdx.x;
  const int lane = tid & 63;
  const int kh = tid >> 6;
  const int col = lane & 15;
  const int kslot = lane >> 4;

  float* cst = c_f + ROLE * 32768;
  const float* gxbase = gx + (ROLE ? 4096 : 0);
  const int cb = tid >> 4, cul = tid & 15, cu = u0 + cul;

  const _Float16* pkbase = Pk + ((size_t)(jb * 8 + kh) * S) * 4 * 512 + lane * 8;
  const int a0off = col * 2056 + kh * S * 32 + kslot * 8;
  const int a1off = a0off + 16 * 2056;

  // weights pinned in registers for the whole recurrence
  f16x8 wreg[S * 4];
#pragma unroll
  for (int i = 0; i < S * 4; ++i) wreg[i] = *(const f16x8*)(pkbase + i * 512);

  for (int p = 0; p <= 64; ++p) {
    const bool active = (ROLE == 0) ? (p < 64) : (p > 0);
    if (active) {
      const int t = (ROLE == 0) ? p : p - 1;
      const _Float16* h0r = h0S + (size_t)p * 32768;
      _Float16* h0w = h0S + (size_t)(p + 1) * 32768;
      const _Float16* h1r = h1S + (size_t)(p - 1) * 32768;
      _Float16* h1w = h1S + (size_t)p * 32768;
      const float* ipfr; float* ipfw;
      if (p & 1) { ipfr = ipfA; ipfw = ipfB; }
      else       { ipfr = ipfB; ipfw = ipfA; }

      const float* gxr = gxbase + (size_t)(t * 32 + cb) * 8192;
      float pg0 = gxr[cu], pg1 = gxr[1024 + cu], pg2 = gxr[2048 + cu], pg3 = gxr[3072 + cu];
      float pc = cst[cb * 1024 + cu];
      float px = 0.f, pip = 0.f;
      if (ROLE == 0) px = x_f[(size_t)(t * 32 + cb) * 1024 + cu];
      else           pip = ALOAD(ipfr + cb * 1024 + cu);

      // ---- state -> LDS (plain cached loads; write-once-fresh addresses) ----
#pragma unroll
      for (int hf = 0; hf < NHALF; ++hf) {
        f16x8 sreg[8];
#pragma unroll
        for (int i = 0; i < 8; ++i) {
          int fr = (hf * 8 + i) * 512 + tid;
          int row = fr >> RSH, k8 = fr & K8M;
          const _Float16* s;
          if (ROLE == 0) s = h0r + row * 1024 + k8 * 8;
          else           s = (k8 < 128) ? (h0r + row * 1024 + k8 * 8)
                                        : (h1r + row * 1024 + (k8 - 128) * 8);
          sreg[i] = *(const f16x8*)s;
        }
#pragma unroll
        for (int i = 0; i < 8; ++i) {
          int fr = (hf * 8 + i) * 512 + tid;
          int row = fr >> RSH, k8 = fr & K8M;
          *(f16x8*)(As + row * 2056 + k8 * 8) = sreg[i];
        }
      }
      __syncthreads();

      f32x4 acc[2][4] = {};
#pragma unroll
      for (int s2 = 0; s2 < S; ++s2) {
        f16x8 a0 = *(const f16x8*)(As + a0off + s2 * 32);
        f16x8 a1 = *(const f16x8*)(As + a1off + s2 * 32);
        acc[0][0] = __builtin_amdgcn_mfma_f32_16x16x32_f16(a0, wreg[s2 * 4 + 0], acc[0][0], 0, 0, 0);
        acc[1][0] = __builtin_amdgcn_mfma_f32_16x16x32_f16(a1, wreg[s2 * 4 + 0], acc[1][0], 0, 0, 0);
        acc[0][1] = __builtin_amdgcn_mfma_f32_16x16x32_f16(a0, wreg[s2 * 4 + 1], acc[0][1], 0, 0, 0);
        acc[1][1] = __builtin_amdgcn_mfma_f32_16x16x32_f16(a1, wreg[s2 * 4 + 1], acc[1][1], 0, 0, 0);
        acc[0][2] = __builtin_amdgcn_mfma_f32_16x16x32_f16(a0, wreg[s2 * 4 + 2], acc[0][2], 0, 0, 0);
        acc[1][2] = __builtin_amdgcn_mfma_f32_16x16x32_f16(a1, wreg[s2 * 4 + 2], acc[1][2], 0, 0, 0);
        acc[0][3] = __builtin_amdgcn_mfma_f32_16x16x32_f16(a0, wreg[s2 * 4 + 3], acc[0][3], 0, 0, 0);
        acc[1][3] = __builtin_amdgcn_mfma_f32_16x16x32_f16(a1, wreg[s2 * 4 + 3], acc[1][3], 0, 0, 0);
      }
      __syncthreads();

      float (*gs)[32][68] = (float (*)[32][68])(void*)As;
      const int rl = kslot * 4;
      if (kh < 4) {
#pragma unroll
        for (int m = 0; m < 2; ++m)
#pragma unroll
          for (int g = 0; g < 4; ++g)
#pragma unroll
            for (int j = 0; j < 4; ++j)
              gs[kh][m * 16 + rl + j][g * 16 + col] = acc[m][g][j];
      }
      __syncthreads();
      if (kh >= 4) {
#pragma unroll
        for (int m = 0; m < 2; ++m)
#pragma unroll
          for (int g = 0; g < 4; ++g)
#pragma unroll
            for (int j = 0; j < 4; ++j)
              gs[kh - 4][m * 16 + rl + j][g * 16 + col] += acc[m][g][j];
      }
      __syncthreads();

      {
        float ig = pg0, fg = pg1, gg = pg2, og = pg3;
#pragma unroll
        for (int cc = 0; cc < 4; ++cc) {
          ig += gs[cc][cb][cul];
          fg += gs[cc][cb][16 + cul];
          gg += gs[cc][cb][32 + cul];
          og += gs[cc][cb][48 + cul];
        }
        float si = 1.f / (1.f + expf(-ig));
        float sf = 1.f / (1.f + expf(-fg));
        float so = 1.f / (1.f + expf(-og));
        float ci = sf * pc + si * tanhf(gg);
        float hi = so * tanhf(ci);
        cst[cb * 1024 + cu] = ci;
        if (t == 63) {
          outHT[ROLE * 32768 + cb * 1024 + cu] = hi;
          outCT[ROLE * 32768 + cb * 1024 + cu] = ci;
        }
        if (ROLE == 0) {
          float hn = __shfl_down(hi, 1);
          float ipv = hi + px;
          float ipn = __shfl_down(ipv, 1);
          if ((cul & 1) == 0) {
            union { _Float16 h[2]; u32 v; } ph;
            ph.h[0] = (_Float16)hi; ph.h[1] = (_Float16)hn;
            ASTORE((u32*)(h0w + cb * 1024 + cu), ph.v);
            union { float f[2]; u64 v; } pi;
            pi.f[0] = ipv; pi.f[1] = ipn;
            ASTORE((u64*)(ipfw + cb * 1024 + cu), pi.v);
          }
        } else {
          float hn = __shfl_down(hi, 1);
          float ro = hi + pip;
          float rn = __shfl_down(ro, 1);
          if ((cul & 1) == 0) {
            union { _Float16 h[2]; u32 v; } ph;
            ph.h[0] = (_Float16)hi; ph.h[1] = (_Float16)hn;
            ASTORE((u32*)(h1w + cb * 1024 + cu), ph.v);
            union { _Float16 h[2]; u32 v; } po;
            po.h[0] = (_Float16)ro; po.h[1] = (_Float16)rn;
            ASTORE((u32*)(outs_h + (size_t)(t * 32 + cb) * 1024 + cu), po.v);
          }
          outs_f[(size_t)(t * 32 + cb) * 1024 + cu] = ro;
        }
      }
    }
    gbar(bar);  // every phase, incl. last -> gen ends at 65
  }
}

// ---------------- clsW f32->f16 conversion by consumer blocks ----------------
__device__ __forceinline__ void conv_clsW(const float* __restrict__ src,
                                          _Float16* __restrict__ dst, int cb) {
  for (int i = cb * 512 + threadIdx.x; i < 4096000; i += 65536) {
    const f32x4* s = (const f32x4*)(src + (size_t)i * 8);
    f32x4 v0 = __builtin_nontemporal_load(s);
    f32x4 v1 = __builtin_nontemporal_load(s + 1);
    union { _Float16 h[8]; u64 q[2]; } o;
    o.h[0] = (_Float16)v0.x; o.h[1] = (_Float16)v0.y;
    o.h[2] = (_Float16)v0.z; o.h[3] = (_Float16)v0.w;
    o.h[4] = (_Float16)v1.x; o.h[5] = (_Float16)v1.y;
    o.h[6] = (_Float16)v1.z; o.h[7] = (_Float16)v1.w;
    u64* d = (u64*)(dst + (size_t)i * 8);
    ASTORE(d, o.q[0]);
    ASTORE(d + 1, o.q[1]);
  }
}

// ---------------- logits GEMM consumer: 256x256 tiles, dynamic work-steal ----------------
__device__ __forceinline__ void run_consumer(
    const _Float16* __restrict__ outs_h, const _Float16* __restrict__ clsW_h,
    const float* __restrict__ cls_b, float* __restrict__ out, int* bar, _Float16* lds) {
  __shared__ int tau_s;
  const int tid = threadIdx.x;
  const int lane = tid & 63;
  const int w = tid >> 6;
  const int wm = w >> 2, wn = w & 3;      // 2x4 wave grid; wave tile 128x64
  int* gen = bar + 544;
  int* wcnt = bar + 576;
  const int r0 = tid & 255, kb0 = tid >> 8;

  if (tid == 0) {
    while (ALOAD(bar + 608) < 128) __builtin_amdgcn_s_sleep(16);
  }
  __syncthreads();

  for (;;) {
    if (tid == 0) tau_s = __hip_atomic_fetch_add(wcnt, 1, __ATOMIC_RELAXED, __HIP_MEMORY_SCOPE_AGENT);
    __syncthreads();
    int tau = tau_s;
    if (tau >= 1000) break;
    int m = tau / 125, nt = tau - m * 125;
    if (tid == 0) {
      int need = 8 * m + 9; if (need > 65) need = 65;
      while (ALOAD(gen) < need) __builtin_amdgcn_s_sleep(64);
    }
    __syncthreads();

    const _Float16* Ab = outs_h + (size_t)m * 256 * 1024;
    const _Float16* Bb = clsW_h + (size_t)nt * 256 * 1024;
    f16x8 pa0, pa1, pb0, pb1;
    pa0 = *(const f16x8*)(Ab + r0 * 1024 + kb0 * 8);
    pa1 = *(const f16x8*)(Ab + r0 * 1024 + (kb0 + 2) * 8);
    pb0 = *(const f16x8*)(Bb + r0 * 1024 + kb0 * 8);
    pb1 = *(const f16x8*)(Bb + r0 * 1024 + (kb0 + 2) * 8);
    f32x4 acc[8][4] = {};
    for (int kc = 0; kc < 32; ++kc) {
      _Float16* Ac = lds + (kc & 1) * 8192;
      _Float16* Bc = lds + 16384 + (kc & 1) * 8192;
      *(f16x8*)(Ac + kb0 * 2048 + r0 * 8) = pa0;
      *(f16x8*)(Ac + (kb0 + 2) * 2048 + r0 * 8) = pa1;
      *(f16x8*)(Bc + kb0 * 2048 + r0 * 8) = pb0;
      *(f16x8*)(Bc + (kb0 + 2) * 2048 + r0 * 8) = pb1;
      if (kc + 1 < 32) {
        int ko = (kc + 1) * 32;
        pa0 = *(const f16x8*)(Ab + r0 * 1024 + ko + kb0 * 8);
        pa1 = *(const f16x8*)(Ab + r0 * 1024 + ko + (kb0 + 2) * 8);
        pb0 = *(const f16x8*)(Bb + r0 * 1024 + ko + kb0 * 8);
        pb1 = *(const f16x8*)(Bb + r0 * 1024 + ko + (kb0 + 2) * 8);
      }
      __syncthreads();
      const int kb = lane >> 4;
      f16x8 af[8], bf[4];
#pragma unroll
      for (int mf = 0; mf < 8; ++mf) {
        int row = wm * 128 + mf * 16 + (lane & 15);
        af[mf] = *(const f16x8*)(Ac + kb * 2048 + row * 8);
      }
#pragma unroll
      for (int nf = 0; nf < 4; ++nf) {
        int row = wn * 64 + nf * 16 + (lane & 15);
        bf[nf] = *(const f16x8*)(Bc + kb * 2048 + row * 8);
      }
#pragma unroll
      for (int mf = 0; mf < 8; ++mf)
#pragma unroll
        for (int nf = 0; nf < 4; ++nf)
          acc[mf][nf] = __builtin_amdgcn_mfma_f32_16x16x32_f16(af[mf], bf[nf], acc[mf][nf], 0, 0, 0);
    }
    const int rl = (lane >> 4) * 4;
#pragma unroll
    for (int mf = 0; mf < 8; ++mf) {
#pragma unroll
      for (int nf = 0; nf < 4; ++nf) {
#pragma unroll
        for (int j = 0; j < 4; ++j) {
          int rg = m * 256 + wm * 128 + mf * 16 + rl + j;
          int tt = rg >> 5, b = rg & 31;
          int ng = nt * 256 + wn * 64 + nf * 16 + (lane & 15);
          __builtin_nontemporal_store(acc[mf][nf][j] + cls_b[ng],
                                      &out[(size_t)(b * 64 + tt) * 32000 + ng]);
        }
      }
    }
  }
}

__global__ __launch_bounds__(512, 1) void k_lstm_fused(
    const _Float16* __restrict__ Pk0, const _Float16* __restrict__ Pk1,
    const float* __restrict__ gx, const float* __restrict__ x_f,
    float* __restrict__ c_f,
    _Float16* __restrict__ h0S, _Float16* __restrict__ h1S,
    float* __restrict__ ipfA, float* __restrict__ ipfB,
    float* __restrict__ outs_f, _Float16* __restrict__ outs_h,
    const float* __restrict__ cls_W, _Float16* __restrict__ clsW_h,
    const float* __restrict__ cls_b,
    float* __restrict__ out_logits,
    float* __restrict__ outHT, float* __restrict__ outCT,
    int* bar) {
  __shared__ _Float16 As[32 * 2056];  // 131,584 B (1 block/CU -> 256 blocks co-resident)
  const int bid = blockIdx.x;
  if (bid < 64) {
    run_phases<0>(bid & 63, Pk0, gx, x_f, c_f, h0S, h1S,
                  ipfA, ipfB, outs_f, outs_h, outHT, outCT, bar, As);
  } else if (bid < 128) {
    run_phases<1>(bid & 63, Pk1, gx, x_f, c_f, h0S, h1S,
                  ipfA, ipfB, outs_f, outs_h, outHT, outCT, bar, As);
  } else {
    conv_clsW(cls_W, clsW_h, bid - 128);
    __syncthreads();
    if (threadIdx.x == 0)
      __hip_atomic_fetch_add(bar + 608, 1, __ATOMIC_RELAXED, __HIP_MEMORY_SCOPE_AGENT);
  }
  run_consumer(outs_h, clsW_h, cls_b, out_logits, bar, As);
}

// ---------------- batched dot-attention + softmax ----------------
__global__ __launch_bounds__(256) void k_attn(const float* __restrict__ outs,
                                              const float* __restrict__ enc,
                                              float* __restrict__ att) {
  __shared__ float o_s[8][1024];
  __shared__ float sc[8][128];
  const int tid = threadIdx.x;
  const int lane = tid & 63;
  const int w = tid >> 6;
  const int b = blockIdx.x >> 3;
  const int t0 = (blockIdx.x & 7) * 8;
#pragma unroll
  for (int ii = 0; ii < 8; ++ii) {
    int idx = tid + ii * 256;
    int tt = idx >> 8, c4 = idx & 255;
    ((float4*)&o_s[tt][0])[c4] =
        *(const float4*)(outs + (size_t)((t0 + tt) * 32 + b) * 1024 + (size_t)c4 * 4);
  }
  __syncthreads();
  for (int si = 0; si < 32; ++si) {
    int s = w * 32 + si;
    float av[8] = {0, 0, 0, 0, 0, 0, 0, 0};
    const float* er = enc + (size_t)(b * 128 + s) * 1024;
#pragma unroll
    for (int i = 0; i < 4; ++i) {
      int k = i * 256 + lane * 4;
      float4 e = *(const float4*)(er + k);
#pragma unroll
      for (int tt = 0; tt < 8; ++tt) {
        float4 o = *(const float4*)&o_s[tt][k];
        av[tt] += e.x * o.x + e.y * o.y + e.z * o.z + e.w * o.w;
      }
    }
#pragma unroll
    for (int tt = 0; tt < 8; ++tt) {
      float v = av[tt];
#pragma unroll
      for (int off = 32; off > 0; off >>= 1) v += __shfl_down(v, off);
      if (lane == 0) sc[tt][s] = v;
    }
  }
  __syncthreads();
#pragma unroll
  for (int pp = 0; pp < 2; ++pp) {
    int tt = w + pp * 4;
    float a = sc[tt][lane], b2 = sc[tt][64 + lane];
    float m = fmaxf(a, b2);
#pragma unroll
    for (int off = 32; off > 0; off >>= 1) m = fmaxf(m, __shfl_xor(m, off));
    float e0 = expf(a - m), e1 = expf(b2 - m);
    float ss = e0 + e1;
#pragma unroll
    for (int off = 32; off > 0; off >>= 1) ss += __shfl_xor(ss, off);
    float r = 1.f / ss;
    att[(size_t)b * 8192 + (size_t)lane * 64 + t0 + tt] = e0 * r;
    att[(size_t)b * 8192 + (size_t)(64 + lane) * 64 + t0 + tt] = e1 * r;
  }
}

extern "C" void kernel_launch(void* const* d_in, const int* in_sizes, int n_in,
                              void* d_out, int out_size, void* d_ws, size_t ws_size,
                              hipStream_t stream) {
  const int*   dec   = (const int*)d_in[0];
  const float* h0    = (const float*)d_in[1];
  const float* c0    = (const float*)d_in[2];
  const float* enc   = (const float*)d_in[3];
  const float* emb   = (const float*)d_in[4];
  const float* W_ih  = (const float*)d_in[5];
  const float* W_hh  = (const float*)d_in[6];
  const float* b_ih  = (const float*)d_in[7];
  const float* b_hh  = (const float*)d_in[8];
  const float* cls_W = (const float*)d_in[9];
  const float* cls_b = (const float*)d_in[10];
  float* out = (float*)d_out;
  char* ws = (char*)d_ws;

  float*    x_f    = (float*)(ws + 0);                // [2048][1024] f32, ends 8388608
  _Float16* Pk0    = (_Float16*)(ws + 8388608);       // 8MB packed Whh0, ends 16777216
  _Float16* h0S    = (_Float16*)(ws + 16777216);      // 65 slots, ends 21037056
  _Float16* h1S    = (_Float16*)(ws + 21037056);      // 65 slots, ends 25296896
  _Float16* Pk1    = (_Float16*)(ws + 29360128);      // 16MB, ends 46137344
  _Float16* clsW_h = (_Float16*)(ws + 46137344);      // 65.5MB, ends 111673344 (filled in-kernel)
  _Float16* Wih_h  = (_Float16*)(ws + 54657024);      // 16.7MB inside clsW_h, ends 71434240
  _Float16* x_h    = (_Float16*)(ws + 71434240);      // 4MB inside clsW_h, ends 75628544
                                                      // (Wih_h/x_h dead after k_gemm0b; conv_clsW
                                                      //  overwrites them during fused — consumers
                                                      //  read clsW_h only after bar[608]==128)
  float*    gx     = (float*)(ws + 111673344);        // [2048][8192] f32, ends 178782208
  float*    outs_f = (float*)(ws + 178782208);        // 8MB, ends 187170816
  _Float16* outs_h = (_Float16*)(ws + 187170816);     // 4MB, ends 191365120
  float*    c_f    = (float*)(ws + 191627264);        // [2][32][1024] f32
  int*      bar    = (int*)(ws + 192151552);          // 640 ints
  float*    ipfA   = (float*)(ws + 192155648);        // [32][1024] f32
  float*    ipfB   = (float*)(ws + 192286720);        // end 192417792

  k_prep<<<10496, 256, 0, stream>>>(W_ih, Wih_h, dec, emb, x_f, x_h,
                                    W_hh, Pk0, Pk1, h0, c0, c_f, h0S, h1S, bar);
  k_gemm0b<<<dim3(32, 8), 512, 0, stream>>>(x_h, Wih_h, b_ih, b_hh, gx);

  k_lstm_fused<<<256, 512, 0, stream>>>(Pk0, Pk1, gx, x_f, c_f,
                                        h0S, h1S, ipfA, ipfB,
                                        outs_f, outs_h, cls_W, clsW_h, cls_b, out,
                                        out + (size_t)65536000, out + (size_t)65601536,
                                        bar);

  k_attn<<<256, 256, 0, stream>>>(outs_f, enc, out + (size_t)65667072);
}